// Round 7
// baseline (6937.840 us; speedup 1.0000x reference)
//
#include <hip/hip_runtime.h>
#include <math.h>

#define NN 4096
#define TT 365
#define FF 16
#define HH 32

typedef _Float16 f16;
typedef __attribute__((ext_vector_type(8))) _Float16 f16x8;
typedef __attribute__((ext_vector_type(16))) float f32x16;

__device__ __forceinline__ float sigf(float x){ return 1.0f/(1.0f+__expf(-x)); }
__device__ __forceinline__ float thf(float x){
    x = fminf(fmaxf(x,-15.0f),15.0f);
    float e = __expf(2.0f*x);
    return (e-1.0f)/(e+1.0f);
}

// Pre-pack A into 32x32x16 MFMA A-fragment order, fp16.
// f16x8 index: (rg*256 + kc)*64 + lane ;  m = rg*32 + (lane&31),
// k = kc*16 + ((lane>>5)<<3) + j   (j = elem 0..7)
__global__ __launch_bounds__(256)
void prep_A(const float* __restrict__ A, f16* __restrict__ Af){
    size_t i = (size_t)blockIdx.x*256 + threadIdx.x;   // 2,097,152 f16x8 frags
    int lane = (int)(i & 63);
    int kc   = (int)((i>>6) & 255);
    int rg   = (int)(i>>14);
    int m  = rg*32 + (lane&31);
    int k0 = kc*16 + ((lane>>5)<<3);
    const float* src = A + (size_t)m*NN + k0;
    float4 a = *(const float4*)src;
    float4 b = *(const float4*)(src+4);
    float v[8] = {a.x,a.y,a.z,a.w,b.x,b.y,b.z,b.w};
    f16x8 vh;
    #pragma unroll
    for (int j=0;j<8;++j) vh[j] = (f16)v[j];
    ((f16x8*)Af)[i] = vh;
}

// Initial G in 32x32x16 B-fragment order; zero h/c state.
// f16 index for G[k][n]: ((kc*2 + ct)*64 + (n&31) + (((k>>3)&1)<<5))*8 + (k&7)
//   kc = k>>4, ct = n>>5
__global__ __launch_bounds__(256)
void init_G(f16* __restrict__ G, float* __restrict__ hs, float* __restrict__ cs,
            const float* __restrict__ bgh, const float* __restrict__ bgc){
    int i = blockIdx.x*256 + threadIdx.x;   // k*64+n
    int k = i>>6, n = i&63;
    float v = (n<HH) ? bgh[n] : bgc[n-HH];
    size_t idx = (((size_t)(k>>4)*2 + (n>>5))*64 + ((n&31) + (((k>>3)&1)<<5)))*8 + (k&7);
    G[idx] = (f16)v;
    if (i < NN*HH){ hs[i]=0.f; cs[i]=0.f; }
}

// MM kernel: grid 512 = 128 row-groups x 4 k-quarters, 512 thr (8 waves),
// 2 blocks/CU. Block covers 32 rows x 1024 k. Wave w: 8 kc-chunks (k16 each):
// per chunk 1 A-load + 2 G-loads (16B) + 2 mfma_32x32x16. 2-stage LDS reduce
// of 8 wave-partials -> Pbuf[kq][rg][32][64] fp32.
__global__ __launch_bounds__(512, 4)
void mm_kernel(const f16* __restrict__ Af, const f16* __restrict__ Gin,
               float* __restrict__ Pbuf)
{
    __shared__ float red[16384];         // [8][32][64] fp32 = 64 KB
    const int tid  = threadIdx.x;
    const int w    = tid >> 6;           // wave 0..7
    const int lane = tid & 63;
    const int rg   = blockIdx.x >> 2;    // row-group 0..127 (32 rows)
    const int kq   = blockIdx.x & 3;     // k-quarter (1024 k = 64 kc)

    const int kcBeg = kq*64 + w*8;
    const f16x8* Ahp = (const f16x8*)Af;
    const f16x8* Gf  = (const f16x8*)Gin;
    size_t aIdx = ((size_t)rg*256 + kcBeg)*64 + lane;
    size_t gIdx = ((size_t)kcBeg*2)*64 + lane;

    f32x16 acc0 = {}, acc1 = {};
    #pragma unroll
    for (int kc = 0; kc < 8; ++kc, aIdx += 64, gIdx += 128){
        f16x8 a0 = Ahp[aIdx];
        f16x8 g0 = Gf[gIdx], g1 = Gf[gIdx+64];
        acc0 = __builtin_amdgcn_mfma_f32_32x32x16_f16(a0, g0, acc0, 0,0,0);
        acc1 = __builtin_amdgcn_mfma_f32_32x32x16_f16(a0, g1, acc1, 0,0,0);
    }
    // C/D layout (m74/m101): col = lane&31, row = (reg&3) + 8*(reg>>2) + 4*(lane>>5)
    const int c0 = lane & 31;
    const int rbase = (lane>>5)<<2;
    if (w < 4){
        #pragma unroll
        for (int reg = 0; reg < 16; ++reg){
            int r = (reg&3) + ((reg>>2)<<3) + rbase;
            red[(w<<11) + r*64 + c0]      = acc0[reg];
            red[(w<<11) + r*64 + 32 + c0] = acc1[reg];
        }
    }
    __syncthreads();
    if (w >= 4){
        #pragma unroll
        for (int reg = 0; reg < 16; ++reg){
            int r = (reg&3) + ((reg>>2)<<3) + rbase;
            red[((w-4)<<11) + r*64 + c0]      += acc0[reg];
            red[((w-4)<<11) + r*64 + 32 + c0] += acc1[reg];
        }
    }
    __syncthreads();
    {   // final: 512 threads x 4 consecutive elems; sum 4 slabs; float4 store
        int e = tid*4;
        float4 s0 = *(const float4*)(red + e);
        float4 s1 = *(const float4*)(red + 2048 + e);
        float4 s2 = *(const float4*)(red + 4096 + e);
        float4 s3 = *(const float4*)(red + 6144 + e);
        float4 s;
        s.x = s0.x+s1.x+s2.x+s3.x; s.y = s0.y+s1.y+s2.y+s3.y;
        s.z = s0.z+s1.z+s2.z+s3.z; s.w = s0.w+s1.w+s2.w+s3.w;
        *(float4*)(Pbuf + ((size_t)kq*128 + rg)*2048 + e) = s;
    }
}

// Cell kernel: grid 256 bands x 512 threads. Sums the 4 k-quarter partials,
// tanh, then row-local LSTM + fusion + next-G fragment write + output head.
// All cross-thread LDS traffic stays within a 32-lane row group -> no barriers.
__global__ __launch_bounds__(512)
void cell_kernel(const float* __restrict__ Pbuf,
                 const float* __restrict__ x, const float* __restrict__ W_out,
                 const float* __restrict__ b_out,
                 const float* __restrict__ Wgh, const float* __restrict__ bgh,
                 const float* __restrict__ Wgc, const float* __restrict__ bgc,
                 const float* __restrict__ Whc, const float* __restrict__ Whp,
                 const float* __restrict__ bh,
                 const float* __restrict__ Wcc, const float* __restrict__ Wcp,
                 const float* __restrict__ bc,
                 const float* __restrict__ K, const float* __restrict__ R,
                 const float* __restrict__ bias,
                 f16* __restrict__ Gout,
                 float* __restrict__ h_state, float* __restrict__ c_state,
                 float* __restrict__ out, int t)
{
    __shared__ float smem[6000];         // 24 KB
    float* gts    = smem;                // [16][129]
    float* hgcg   = smem + 2064;         // [16][65]
    float* hprevL = smem + 3104;         // [16][33]
    float* xs     = smem + 3632;         // [16][16]
    float* hcur   = smem + 3888;         // [16][33]
    float* ccur   = smem + 4416;
    float* hupd   = smem + 4944;
    float* cupd   = smem + 5472;

    const int tid = threadIdx.x;
    const int r2  = tid >> 5;            // local row 0..15
    const int j   = tid & 31;            // h-dim 0..31
    const int band = blockIdx.x;
    const int row = band*16 + r2;
    const int rg  = band >> 1;
    const int rIn = (band & 1)*16 + r2;  // row within 32-row group

    // sum 4 k-quarter partials + tanh for cols j and j+32
    #pragma unroll
    for (int half = 0; half < 2; ++half){
        int n = j + half*32;
        float s = 0.f;
        #pragma unroll
        for (int q = 0; q < 4; ++q)
            s += Pbuf[((size_t)q*128 + rg)*2048 + rIn*64 + n];
        hgcg[r2*65 + n] = thf(s);
    }

    float hp = h_state[(size_t)row*HH + j];
    hprevL[r2*33 + j] = hp;
    if (j < 16) xs[r2*16 + j] = x[((size_t)row*TT + t)*FF + j];

    // gates: thread computes gate cols [j*4, j*4+4)
    float g4[4];
    #pragma unroll
    for (int q = 0; q < 4; ++q) g4[q] = bias[j*4 + q];
    #pragma unroll
    for (int f = 0; f < FF; ++f){
        float xv = xs[r2*16 + f];
        float4 k4 = *(const float4*)(K + f*128 + j*4);
        g4[0] += xv*k4.x; g4[1] += xv*k4.y; g4[2] += xv*k4.z; g4[3] += xv*k4.w;
    }
    #pragma unroll
    for (int i = 0; i < HH; ++i){
        float hv = hprevL[r2*33 + i];
        float4 r4 = *(const float4*)(R + i*128 + j*4);
        g4[0] += hv*r4.x; g4[1] += hv*r4.y; g4[2] += hv*r4.z; g4[3] += hv*r4.w;
    }
    #pragma unroll
    for (int q = 0; q < 4; ++q) gts[r2*129 + j*4 + q] = g4[q];

    // LSTM cell, dim j (gate order i,f,g,o)
    float gi = gts[r2*129 + j],      gf = gts[r2*129 + 32 + j];
    float gg = gts[r2*129 + 64 + j], go = gts[r2*129 + 96 + j];
    float cp = c_state[(size_t)row*HH + j];
    float cc = sigf(gf)*cp + sigf(gi)*thf(gg);
    float hc = sigf(go)*thf(cc);
    hcur[r2*33 + j] = hc;
    ccur[r2*33 + j] = cc;

    // fusion
    float s = bh[j], u = bc[j];
    #pragma unroll
    for (int i = 0; i < HH; ++i){
        float hcv = hcur[r2*33 + i], hgv = hgcg[r2*65 + i];
        float ccv = ccur[r2*33 + i], cgv = hgcg[r2*65 + 32 + i];
        s += hcv*Whc[i*32 + j] + hgv*Whp[i*32 + j];
        u += ccv*Wcc[i*32 + j] + cgv*Wcp[i*32 + j];
    }
    float hu = sigf(s), cu = sigf(u);
    hupd[r2*33 + j] = hu;
    cupd[r2*33 + j] = cu;
    h_state[(size_t)row*HH + j] = hu;
    c_state[(size_t)row*HH + j] = cu;

    // G(t+1), written straight into 32x32x16 B-fragment order
    float gh = bgh[j], gc = bgc[j];
    #pragma unroll
    for (int i = 0; i < HH; ++i){
        float hv = hupd[r2*33 + i], cv = cupd[r2*33 + i];
        gh += hv*Wgh[i*32 + j];
        gc += cv*Wgc[i*32 + j];
    }
    {
        const int kc = row>>4;
        const int kb = ((row>>3)&1)<<5;
        const int kj = row&7;
        // n = j (< 32): ct = 0 ; n = 32+j: ct = 1
        size_t i0 = (((size_t)kc*2 + 0)*64 + (j + kb))*8 + kj;
        size_t i1 = (((size_t)kc*2 + 1)*64 + (j + kb))*8 + kj;
        Gout[i0] = (f16)gh;
        Gout[i1] = (f16)gc;
    }

    // fused output head
    float p = hu * W_out[j];
    #pragma unroll
    for (int off = 16; off; off >>= 1) p += __shfl_down(p, off, 32);
    if (j == 0) out[(size_t)t*NN + row] = p + b_out[0];
}

extern "C" void kernel_launch(void* const* d_in, const int* in_sizes, int n_in,
                              void* d_out, int out_size, void* d_ws, size_t ws_size,
                              hipStream_t stream)
{
    const float* x     = (const float*)d_in[0];
    const float* A     = (const float*)d_in[1];
    const float* W_out = (const float*)d_in[2];
    const float* b_out = (const float*)d_in[3];
    const float* Wgh   = (const float*)d_in[4];
    const float* bgh   = (const float*)d_in[5];
    const float* Wgc   = (const float*)d_in[6];
    const float* bgc   = (const float*)d_in[7];
    const float* Whc   = (const float*)d_in[8];
    const float* Whp   = (const float*)d_in[9];
    const float* bh    = (const float*)d_in[10];
    const float* Wcc   = (const float*)d_in[11];
    const float* Wcp   = (const float*)d_in[12];
    const float* bc    = (const float*)d_in[13];
    const float* K     = (const float*)d_in[14];
    const float* R     = (const float*)d_in[15];
    const float* bias  = (const float*)d_in[16];
    float* out = (float*)d_out;

    // ws: Af 32MB | G double-buffer 2x512KB | Pbuf 2MB | h/c state 1MB
    f16* Af = (f16*)d_ws;
    f16* G0 = Af + (size_t)NN*NN;
    f16* G1 = G0 + (size_t)NN*64;
    float* Pbuf = (float*)(G1 + (size_t)NN*64);
    float* hs = Pbuf + (size_t)4*128*2048;
    float* cs = hs + (size_t)NN*HH;

    prep_A<<<dim3(8192), dim3(256), 0, stream>>>(A, Af);
    init_G<<<dim3(1024), dim3(256), 0, stream>>>(G0, hs, cs, bgh, bgc);

    for (int t = 0; t < TT; ++t){
        const f16* Gin = (t & 1) ? G1 : G0;
        f16*       Gout = (t & 1) ? G0 : G1;
        mm_kernel<<<dim3(512), dim3(512), 0, stream>>>(Af, Gin, Pbuf);
        cell_kernel<<<dim3(256), dim3(512), 0, stream>>>(
            Pbuf, x, W_out, b_out, Wgh, bgh, Wgc, bgc, Whc, Whp, bh,
            Wcc, Wcp, bc, K, R, bias, Gout, hs, cs, out, t);
    }
}

// Round 8
// 6253.942 us; speedup vs baseline: 1.1094x; 1.1094x over previous
//
#include <hip/hip_runtime.h>
#include <math.h>

#define NN 4096
#define TT 365
#define FF 16
#define HH 32

typedef _Float16 f16;
typedef __attribute__((ext_vector_type(8))) _Float16 f16x8;
typedef __attribute__((ext_vector_type(4))) float f32x4;

__device__ __forceinline__ float sigf(float x){ return 1.0f/(1.0f+__expf(-x)); }
__device__ __forceinline__ float thf(float x){
    x = fminf(fmaxf(x,-15.0f),15.0f);
    float e = __expf(2.0f*x);
    return (e-1.0f)/(e+1.0f);
}

// Pre-pack A (fp32 [4096][4096]) into 16x16x32 MFMA A-fragment order, fp16.
// Fragment addr (f16x8 units): (rb*128 + kt)*64 + lane
__global__ __launch_bounds__(256)
void prep_A(const float* __restrict__ A, f16* __restrict__ Af){
    size_t i = (size_t)blockIdx.x*256 + threadIdx.x;   // 2,097,152 f16x8 frags
    int lane = (int)(i & 63);
    int kt   = (int)((i>>6) & 127);
    int rb   = (int)(i>>13);
    int m  = rb*16 + (lane&15);
    int k0 = kt*32 + ((lane>>4)<<3);
    const float* src = A + (size_t)m*NN + k0;
    float4 a = *(const float4*)src;
    float4 b = *(const float4*)(src+4);
    float v[8] = {a.x,a.y,a.z,a.w,b.x,b.y,b.z,b.w};
    f16x8 vh;
    #pragma unroll
    for (int j=0;j<8;++j) vh[j] = (f16)v[j];
    ((f16x8*)Af)[i] = vh;
}

// Initial G (h=c=0 -> cols = biases), fragment-ordered fp16; zero h/c state.
// B-fragment addr (f16 units): ((kt*4 + ct)*64 + (n&15) + ((kr>>3)<<4))*8 + (kr&7)
__global__ __launch_bounds__(256)
void init_G(f16* __restrict__ G, float* __restrict__ hs, float* __restrict__ cs,
            const float* __restrict__ bgh, const float* __restrict__ bgc){
    int i = blockIdx.x*256 + threadIdx.x;   // k*64+n
    int k = i>>6, n = i&63;
    float v = (n<HH) ? bgh[n] : bgc[n-HH];
    int kt = k>>5, kr = k&31;
    size_t idx = (((size_t)kt*4 + (n>>4))*64 + ((n&15) + ((kr>>3)<<4)))*8 + (kr&7);
    G[idx] = (f16)v;
    if (i < NN*HH){ hs[i]=0.f; cs[i]=0.f; }
}

// One time step. 1024 threads = 16 waves, 1 block/CU. Block owns 16 node-rows.
// Timeline: hoisted h/c/x loads -> phase-1 MFMA (wave = k-sixteenth) -> bar ->
// {waves 8-15: slab accumulate | waves 0-7: gate GEMM} -> bar ->
// final reduce + tanh -> bar -> LSTM + fusion + G-write + head (tid<512).
__global__ __launch_bounds__(1024)
void step_kernel(const f16* __restrict__ Af, const f16* __restrict__ Gin,
                 f16* __restrict__ Gout,
                 const float* __restrict__ x, const float* __restrict__ W_out,
                 const float* __restrict__ b_out,
                 const float* __restrict__ Wgh, const float* __restrict__ bgh,
                 const float* __restrict__ Wgc, const float* __restrict__ bgc,
                 const float* __restrict__ Whc, const float* __restrict__ Whp,
                 const float* __restrict__ bh,
                 const float* __restrict__ Wcc, const float* __restrict__ Wcp,
                 const float* __restrict__ bc,
                 const float* __restrict__ K, const float* __restrict__ R,
                 const float* __restrict__ bias,
                 float* __restrict__ h_state, float* __restrict__ c_state,
                 float* __restrict__ out, int t)
{
    __shared__ float smem[14192];        // 56.8 KB
    float* ldsRed = smem;                // [8][16][64] partials (2-stage)
    float* gts    = smem + 8192;         // [16][129] gates (own region now)
    float* hgcg   = smem + 10256;        // [16][65]
    float* hprevL = smem + 11296;        // [16][33]
    float* xs     = smem + 11824;        // [16][16]
    float* hcur   = smem + 12080;        // [16][33]
    float* ccur   = smem + 12608;
    float* hupd   = smem + 13136;
    float* cupd   = smem + 13664;

    const int tid  = threadIdx.x;
    const int w    = tid >> 6;           // wave 0..15 = k-sixteenth
    const int lane = tid & 63;
    const int rb   = blockIdx.x;

    // ---- hoisted state loads: issue first, latency hides under phase 1 ----
    const int r2 = tid >> 5;             // local row 0..15 (tid<512)
    const int j  = tid & 31;             // h-dim 0..31
    const int row = rb*16 + (r2 & 15);
    float cp = 0.f;
    if (tid < 512){
        float hp = h_state[(size_t)row*HH + j];
        cp = c_state[(size_t)row*HH + j];
        hprevL[r2*33 + j] = hp;
        if (j < 16) xs[r2*16 + j] = x[((size_t)row*TT + t)*FF + j];
    }

    // ---------------- phase 1: fp16 MFMA, wave w = 8 kt ----------------
    f32x4 acc[4] = {};
    const f16x8* Ahp = (const f16x8*)Af;
    const f16x8* Gf  = (const f16x8*)Gin;
    size_t aIdx = ((size_t)rb*128 + w*8)*64 + lane;
    size_t gIdx = ((size_t)w*8)*256 + lane;
    #pragma unroll
    for (int kt = 0; kt < 8; ++kt, aIdx += 64, gIdx += 256){
        f16x8 ah = Ahp[aIdx];
        f16x8 g0 = Gf[gIdx], g1 = Gf[gIdx+64], g2 = Gf[gIdx+128], g3 = Gf[gIdx+192];
        acc[0] = __builtin_amdgcn_mfma_f32_16x16x32_f16(ah,g0,acc[0],0,0,0);
        acc[1] = __builtin_amdgcn_mfma_f32_16x16x32_f16(ah,g1,acc[1],0,0,0);
        acc[2] = __builtin_amdgcn_mfma_f32_16x16x32_f16(ah,g2,acc[2],0,0,0);
        acc[3] = __builtin_amdgcn_mfma_f32_16x16x32_f16(ah,g3,acc[3],0,0,0);
    }
    // C/D layout (m89): col = lane&15, row = (lane>>4)*4 + reg
    if (w < 8){
        #pragma unroll
        for (int ct = 0; ct < 4; ++ct)
            #pragma unroll
            for (int r = 0; r < 4; ++r){
                int mrow = ((lane>>4)<<2) + r;
                int mcol = ct*16 + (lane&15);
                ldsRed[(w<<10) + mrow*64 + mcol] = acc[ct][r];
            }
    }
    __syncthreads();

    // ---- overlap window: waves 8-15 accumulate slabs; waves 0-7 do gates ----
    if (w >= 8){
        #pragma unroll
        for (int ct = 0; ct < 4; ++ct)
            #pragma unroll
            for (int r = 0; r < 4; ++r){
                int mrow = ((lane>>4)<<2) + r;
                int mcol = ct*16 + (lane&15);
                ldsRed[((w-8)<<10) + mrow*64 + mcol] += acc[ct][r];
            }
    } else {
        // gates: thread (r2,j) computes gate cols [j*4, j*4+4)
        float g4[4];
        #pragma unroll
        for (int q = 0; q < 4; ++q) g4[q] = bias[j*4 + q];
        #pragma unroll
        for (int f = 0; f < FF; ++f){
            float xv = xs[r2*16 + f];
            float4 k4 = *(const float4*)(K + f*128 + j*4);
            g4[0] += xv*k4.x; g4[1] += xv*k4.y; g4[2] += xv*k4.z; g4[3] += xv*k4.w;
        }
        #pragma unroll
        for (int i = 0; i < HH; ++i){
            float hv = hprevL[r2*33 + i];
            float4 r4 = *(const float4*)(R + i*128 + j*4);
            g4[0] += hv*r4.x; g4[1] += hv*r4.y; g4[2] += hv*r4.z; g4[3] += hv*r4.w;
        }
        #pragma unroll
        for (int q = 0; q < 4; ++q) gts[r2*129 + j*4 + q] = g4[q];
    }
    __syncthreads();

    {   // final reduce: thread tid owns output element tid (16x64 = 1024)
        float s = 0.f;
        #pragma unroll
        for (int ww = 0; ww < 8; ++ww) s += ldsRed[(ww<<10) + tid];
        hgcg[(tid>>6)*65 + (tid&63)] = thf(s);
    }
    __syncthreads();

    // ---------------- phase 2: 512 threads, 1 dim each, no barriers ----------------
    if (tid < 512){
        // LSTM cell, dim j (gate order i,f,g,o); c_prev from register
        float gi = gts[r2*129 + j],      gf = gts[r2*129 + 32 + j];
        float gg = gts[r2*129 + 64 + j], go = gts[r2*129 + 96 + j];
        float cc = sigf(gf)*cp + sigf(gi)*thf(gg);
        float hc = sigf(go)*thf(cc);
        hcur[r2*33 + j] = hc;
        ccur[r2*33 + j] = cc;
        // wave-local row group (32 consecutive lanes) -> in-order, no sync

        // fusion
        float s = bh[j], u = bc[j];
        #pragma unroll
        for (int i = 0; i < HH; ++i){
            float hcv = hcur[r2*33 + i], hgv = hgcg[r2*65 + i];
            float ccv = ccur[r2*33 + i], cgv = hgcg[r2*65 + 32 + i];
            s += hcv*Whc[i*32 + j] + hgv*Whp[i*32 + j];
            u += ccv*Wcc[i*32 + j] + cgv*Wcp[i*32 + j];
        }
        float hu = sigf(s), cu = sigf(u);
        hupd[r2*33 + j] = hu;
        cupd[r2*33 + j] = cu;
        h_state[(size_t)row*HH + j] = hu;
        c_state[(size_t)row*HH + j] = cu;

        // G(t+1), written straight into B-fragment order
        float gh = bgh[j], gc = bgc[j];
        #pragma unroll
        for (int i = 0; i < HH; ++i){
            float hv = hupd[r2*33 + i], cv = cupd[r2*33 + i];
            gh += hv*Wgh[i*32 + j];
            gc += cv*Wgc[i*32 + j];
        }
        {
            const int kt = row>>5, kr = row&31;
            const size_t tb = ((size_t)kt*4)*64;
            size_t i0 = (tb + (size_t)(j>>4)*64 + ((j&15) + ((kr>>3)<<4)))*8 + (kr&7);
            size_t i1 = (tb + (size_t)((HH+j)>>4)*64 + ((j&15) + ((kr>>3)<<4)))*8 + (kr&7);
            Gout[i0] = (f16)gh;
            Gout[i1] = (f16)gc;
        }

        // fused output head
        float p = hu * W_out[j];
        #pragma unroll
        for (int off = 16; off; off >>= 1) p += __shfl_down(p, off, 32);
        if (j == 0) out[(size_t)t*NN + row] = p + b_out[0];
    }
}

extern "C" void kernel_launch(void* const* d_in, const int* in_sizes, int n_in,
                              void* d_out, int out_size, void* d_ws, size_t ws_size,
                              hipStream_t stream)
{
    const float* x     = (const float*)d_in[0];
    const float* A     = (const float*)d_in[1];
    const float* W_out = (const float*)d_in[2];
    const float* b_out = (const float*)d_in[3];
    const float* Wgh   = (const float*)d_in[4];
    const float* bgh   = (const float*)d_in[5];
    const float* Wgc   = (const float*)d_in[6];
    const float* bgc   = (const float*)d_in[7];
    const float* Whc   = (const float*)d_in[8];
    const float* Whp   = (const float*)d_in[9];
    const float* bh    = (const float*)d_in[10];
    const float* Wcc   = (const float*)d_in[11];
    const float* Wcp   = (const float*)d_in[12];
    const float* bc    = (const float*)d_in[13];
    const float* K     = (const float*)d_in[14];
    const float* R     = (const float*)d_in[15];
    const float* bias  = (const float*)d_in[16];
    float* out = (float*)d_out;

    // ws: Af 32MB | G double-buffer 2x512KB | h/c state 1MB
    f16* Af = (f16*)d_ws;
    f16* G0 = Af + (size_t)NN*NN;
    f16* G1 = G0 + (size_t)NN*64;
    float* hs = (float*)(G1 + (size_t)NN*64);
    float* cs = hs + (size_t)NN*HH;

    prep_A<<<dim3(8192), dim3(256), 0, stream>>>(A, Af);
    init_G<<<dim3(1024), dim3(256), 0, stream>>>(G0, hs, cs, bgh, bgc);

    for (int t = 0; t < TT; ++t){
        const f16* Gin = (t & 1) ? G1 : G0;
        f16*       Gout = (t & 1) ? G0 : G1;
        step_kernel<<<dim3(NN/16), dim3(1024), 0, stream>>>(
            Af, Gin, Gout,
            x, W_out, b_out, Wgh, bgh, Wgc, bgc, Whc, Whp, bh,
            Wcc, Wcp, bc, K, R, bias, hs, cs, out, t);
    }
}

// Round 9
// 5882.175 us; speedup vs baseline: 1.1795x; 1.0632x over previous
//
#include <hip/hip_runtime.h>
#include <math.h>

#define NN 4096
#define TT 365
#define FF 16
#define HH 32

typedef _Float16 f16;
typedef __attribute__((ext_vector_type(8))) _Float16 f16x8;
typedef __attribute__((ext_vector_type(4))) float f32x4;

__device__ __forceinline__ float sigf(float x){ return 1.0f/(1.0f+__expf(-x)); }
__device__ __forceinline__ float thf(float x){
    x = fminf(fmaxf(x,-15.0f),15.0f);
    float e = __expf(2.0f*x);
    return (e-1.0f)/(e+1.0f);
}

// Pre-pack A (fp32 [4096][4096]) into 16x16x32 MFMA A-fragment order, fp16.
// Fragment addr (f16x8 units): (rb*128 + kt)*64 + lane
__global__ __launch_bounds__(256)
void prep_A(const float* __restrict__ A, f16* __restrict__ Af){
    size_t i = (size_t)blockIdx.x*256 + threadIdx.x;   // 2,097,152 f16x8 frags
    int lane = (int)(i & 63);
    int kt   = (int)((i>>6) & 127);
    int rb   = (int)(i>>13);
    int m  = rb*16 + (lane&15);
    int k0 = kt*32 + ((lane>>4)<<3);
    const float* src = A + (size_t)m*NN + k0;
    float4 a = *(const float4*)src;
    float4 b = *(const float4*)(src+4);
    float v[8] = {a.x,a.y,a.z,a.w,b.x,b.y,b.z,b.w};
    f16x8 vh;
    #pragma unroll
    for (int j=0;j<8;++j) vh[j] = (f16)v[j];
    ((f16x8*)Af)[i] = vh;
}

// Initial G (h=c=0 -> cols = biases), fragment-ordered fp16; zero h/c state.
// B-fragment addr (f16 units): ((kt*4 + ct)*64 + (n&15) + ((kr>>3)<<4))*8 + (kr&7)
__global__ __launch_bounds__(256)
void init_G(f16* __restrict__ G, float* __restrict__ hs, float* __restrict__ cs,
            const float* __restrict__ bgh, const float* __restrict__ bgc){
    int i = blockIdx.x*256 + threadIdx.x;   // k*64+n
    int k = i>>6, n = i&63;
    float v = (n<HH) ? bgh[n] : bgc[n-HH];
    int kt = k>>5, kr = k&31;
    size_t idx = (((size_t)kt*4 + (n>>4))*64 + ((n&15) + ((kr>>3)<<4)))*8 + (kr&7);
    G[idx] = (f16)v;
    if (i < NN*HH){ hs[i]=0.f; cs[i]=0.f; }
}

// One time step. 1024 threads = 16 waves, 1 block/CU. Block owns 16 node-rows.
// Timeline: hoisted h/c/x/bias loads -> phase-1 MFMA (setprio(1)) -> bar ->
// {waves 8-15: slab accumulate | waves 0-7: gate GEMM} -> bar ->
// final reduce + tanh -> bar -> LSTM + fusion + G-write + head (tid<512).
// Slab bases staggered by +16 floats/wave to rotate LDS bank phase.
__global__ __launch_bounds__(1024)
void step_kernel(const f16* __restrict__ Af, const f16* __restrict__ Gin,
                 f16* __restrict__ Gout,
                 const float* __restrict__ x, const float* __restrict__ W_out,
                 const float* __restrict__ b_out,
                 const float* __restrict__ Wgh, const float* __restrict__ bgh,
                 const float* __restrict__ Wgc, const float* __restrict__ bgc,
                 const float* __restrict__ Whc, const float* __restrict__ Whp,
                 const float* __restrict__ bh,
                 const float* __restrict__ Wcc, const float* __restrict__ Wcp,
                 const float* __restrict__ bc,
                 const float* __restrict__ K, const float* __restrict__ R,
                 const float* __restrict__ bias,
                 float* __restrict__ h_state, float* __restrict__ c_state,
                 float* __restrict__ out, int t)
{
    __shared__ float smem[14320];        // 57.3 KB
    float* ldsRed = smem;                // [8] slabs of 1024, staggered +16/wave
    float* gts    = smem + 8320;         // [16][129] gates
    float* hgcg   = smem + 10384;        // [16][65]
    float* hprevL = smem + 11424;        // [16][33]
    float* xs     = smem + 11952;        // [16][16]
    float* hcur   = smem + 12208;        // [16][33]
    float* ccur   = smem + 12736;
    float* hupd   = smem + 13264;
    float* cupd   = smem + 13792;

    const int tid  = threadIdx.x;
    const int w    = tid >> 6;           // wave 0..15 = k-sixteenth
    const int lane = tid & 63;
    const int rb   = blockIdx.x;

    // ---- hoisted loads: issue first, latency hides under phase 1 ----
    const int r2 = tid >> 5;             // local row 0..15 (tid<512)
    const int j  = tid & 31;             // h-dim 0..31
    const int row = rb*16 + (r2 & 15);
    float cp = 0.f;
    float g4[4] = {0.f,0.f,0.f,0.f};
    if (tid < 512){
        float hp = h_state[(size_t)row*HH + j];
        cp = c_state[(size_t)row*HH + j];
        hprevL[r2*33 + j] = hp;
        if (j < 16) xs[r2*16 + j] = x[((size_t)row*TT + t)*FF + j];
        #pragma unroll
        for (int q = 0; q < 4; ++q) g4[q] = bias[j*4 + q];
    }

    // ---------------- phase 1: fp16 MFMA, wave w = 8 kt ----------------
    f32x4 acc[4] = {};
    const f16x8* Ahp = (const f16x8*)Af;
    const f16x8* Gf  = (const f16x8*)Gin;
    size_t aIdx = ((size_t)rb*128 + w*8)*64 + lane;
    size_t gIdx = ((size_t)w*8)*256 + lane;
    __builtin_amdgcn_s_setprio(1);
    #pragma unroll
    for (int kt = 0; kt < 8; ++kt, aIdx += 64, gIdx += 256){
        f16x8 ah = Ahp[aIdx];
        f16x8 g0 = Gf[gIdx], g1 = Gf[gIdx+64], g2 = Gf[gIdx+128], g3 = Gf[gIdx+192];
        acc[0] = __builtin_amdgcn_mfma_f32_16x16x32_f16(ah,g0,acc[0],0,0,0);
        acc[1] = __builtin_amdgcn_mfma_f32_16x16x32_f16(ah,g1,acc[1],0,0,0);
        acc[2] = __builtin_amdgcn_mfma_f32_16x16x32_f16(ah,g2,acc[2],0,0,0);
        acc[3] = __builtin_amdgcn_mfma_f32_16x16x32_f16(ah,g3,acc[3],0,0,0);
    }
    __builtin_amdgcn_s_setprio(0);

    // C/D layout (m89): col = lane&15, row = (lane>>4)*4 + reg
    // slab base for logical slab s: s*1024 + s*16 (staggers bank phase)
    if (w < 8){
        const int sb = (w<<10) + (w<<4);
        #pragma unroll
        for (int ct = 0; ct < 4; ++ct)
            #pragma unroll
            for (int r = 0; r < 4; ++r){
                int mrow = ((lane>>4)<<2) + r;
                int mcol = ct*16 + (lane&15);
                ldsRed[sb + mrow*64 + mcol] = acc[ct][r];
            }
    }
    __syncthreads();

    // ---- overlap window: waves 8-15 accumulate slabs; waves 0-7 do gates ----
    if (w >= 8){
        const int sb = ((w-8)<<10) + ((w-8)<<4);
        #pragma unroll
        for (int ct = 0; ct < 4; ++ct)
            #pragma unroll
            for (int r = 0; r < 4; ++r){
                int mrow = ((lane>>4)<<2) + r;
                int mcol = ct*16 + (lane&15);
                ldsRed[sb + mrow*64 + mcol] += acc[ct][r];
            }
    } else {
        // gates: thread (r2,j) computes gate cols [j*4, j*4+4)
        #pragma unroll
        for (int f = 0; f < FF; ++f){
            float xv = xs[r2*16 + f];
            float4 k4 = *(const float4*)(K + f*128 + j*4);
            g4[0] += xv*k4.x; g4[1] += xv*k4.y; g4[2] += xv*k4.z; g4[3] += xv*k4.w;
        }
        #pragma unroll
        for (int i = 0; i < HH; ++i){
            float hv = hprevL[r2*33 + i];
            float4 r4 = *(const float4*)(R + i*128 + j*4);
            g4[0] += hv*r4.x; g4[1] += hv*r4.y; g4[2] += hv*r4.z; g4[3] += hv*r4.w;
        }
        #pragma unroll
        for (int q = 0; q < 4; ++q) gts[r2*129 + j*4 + q] = g4[q];
    }
    __syncthreads();

    {   // final reduce: thread tid owns output element tid (16x64 = 1024)
        float s = 0.f;
        #pragma unroll
        for (int ww = 0; ww < 8; ++ww) s += ldsRed[(ww<<10) + (ww<<4) + tid];
        hgcg[(tid>>6)*65 + (tid&63)] = thf(s);
    }
    __syncthreads();

    // ---------------- phase 2: 512 threads, 1 dim each, no barriers ----------------
    if (tid < 512){
        // LSTM cell, dim j (gate order i,f,g,o); c_prev from register
        float gi = gts[r2*129 + j],      gf = gts[r2*129 + 32 + j];
        float gg = gts[r2*129 + 64 + j], go = gts[r2*129 + 96 + j];
        float cc = sigf(gf)*cp + sigf(gi)*thf(gg);
        float hc = sigf(go)*thf(cc);
        hcur[r2*33 + j] = hc;
        ccur[r2*33 + j] = cc;
        // wave-local row group (32 consecutive lanes) -> in-order, no sync

        // fusion
        float s = bh[j], u = bc[j];
        #pragma unroll
        for (int i = 0; i < HH; ++i){
            float hcv = hcur[r2*33 + i], hgv = hgcg[r2*65 + i];
            float ccv = ccur[r2*33 + i], cgv = hgcg[r2*65 + 32 + i];
            s += hcv*Whc[i*32 + j] + hgv*Whp[i*32 + j];
            u += ccv*Wcc[i*32 + j] + cgv*Wcp[i*32 + j];
        }
        float hu = sigf(s), cu = sigf(u);
        hupd[r2*33 + j] = hu;
        cupd[r2*33 + j] = cu;
        h_state[(size_t)row*HH + j] = hu;
        c_state[(size_t)row*HH + j] = cu;

        // G(t+1), written straight into B-fragment order
        float gh = bgh[j], gc = bgc[j];
        #pragma unroll
        for (int i = 0; i < HH; ++i){
            float hv = hupd[r2*33 + i], cv = cupd[r2*33 + i];
            gh += hv*Wgh[i*32 + j];
            gc += cv*Wgc[i*32 + j];
        }
        {
            const int kt = row>>5, kr = row&31;
            const size_t tb = ((size_t)kt*4)*64;
            size_t i0 = (tb + (size_t)(j>>4)*64 + ((j&15) + ((kr>>3)<<4)))*8 + (kr&7);
            size_t i1 = (tb + (size_t)((HH+j)>>4)*64 + ((j&15) + ((kr>>3)<<4)))*8 + (kr&7);
            Gout[i0] = (f16)gh;
            Gout[i1] = (f16)gc;
        }

        // fused output head
        float p = hu * W_out[j];
        #pragma unroll
        for (int off = 16; off; off >>= 1) p += __shfl_down(p, off, 32);
        if (j == 0) out[(size_t)t*NN + row] = p + b_out[0];
    }
}

extern "C" void kernel_launch(void* const* d_in, const int* in_sizes, int n_in,
                              void* d_out, int out_size, void* d_ws, size_t ws_size,
                              hipStream_t stream)
{
    const float* x     = (const float*)d_in[0];
    const float* A     = (const float*)d_in[1];
    const float* W_out = (const float*)d_in[2];
    const float* b_out = (const float*)d_in[3];
    const float* Wgh   = (const float*)d_in[4];
    const float* bgh   = (const float*)d_in[5];
    const float* Wgc   = (const float*)d_in[6];
    const float* bgc   = (const float*)d_in[7];
    const float* Whc   = (const float*)d_in[8];
    const float* Whp   = (const float*)d_in[9];
    const float* bh    = (const float*)d_in[10];
    const float* Wcc   = (const float*)d_in[11];
    const float* Wcp   = (const float*)d_in[12];
    const float* bc    = (const float*)d_in[13];
    const float* K     = (const float*)d_in[14];
    const float* R     = (const float*)d_in[15];
    const float* bias  = (const float*)d_in[16];
    float* out = (float*)d_out;

    // ws: Af 32MB | G double-buffer 2x512KB | h/c state 1MB
    f16* Af = (f16*)d_ws;
    f16* G0 = Af + (size_t)NN*NN;
    f16* G1 = G0 + (size_t)NN*64;
    float* hs = (float*)(G1 + (size_t)NN*64);
    float* cs = hs + (size_t)NN*HH;

    prep_A<<<dim3(8192), dim3(256), 0, stream>>>(A, Af);
    init_G<<<dim3(1024), dim3(256), 0, stream>>>(G0, hs, cs, bgh, bgc);

    for (int t = 0; t < TT; ++t){
        const f16* Gin = (t & 1) ? G1 : G0;
        f16*       Gout = (t & 1) ? G0 : G1;
        step_kernel<<<dim3(NN/16), dim3(1024), 0, stream>>>(
            Af, Gin, Gout,
            x, W_out, b_out, Wgh, bgh, Wgc, bgc, Whc, Whp, bh,
            Wcc, Wcp, bc, K, R, bias, hs, cs, out, t);
    }
}